// Round 16
// baseline (3607.260 us; speedup 1.0000x reference)
//
#include <hip/hip_runtime.h>
#include <hip/hip_bf16.h>
#include <math.h>

#define DD   512
#define NHH  8
#define DHH  64
#define NLL  4
#define NQQ  4
#define CBB  1024
#define DATA 256
#define BB   32
#define TT   512
#define MM   (BB*TT)   // 16384

typedef __attribute__((ext_vector_type(8))) short bf16x8;
typedef __attribute__((ext_vector_type(4))) float f32x4;

// ---------------- block reduce ----------------
__device__ __forceinline__ float blk_reduce(float v, float* red) {
    const int t = threadIdx.x;
    red[t] = v;
    __syncthreads();
    #pragma unroll
    for (int s = 128; s > 0; s >>= 1) {
        if (t < s) red[t] += red[t + s];
        __syncthreads();
    }
    float r = red[0];
    __syncthreads();
    return r;
}

// ---------------- XCD-aware bijective block remap (m204) ----------------
__device__ __forceinline__ int xcd_remap_lin(int orig, int nwg) {
    int xcd = orig & 7;
    int q = nwg >> 3, r = nwg & 7;
    int base = (xcd < r) ? xcd * (q + 1) : r * (q + 1) + (xcd - r) * q;
    return base + (orig >> 3);
}

// ---------------- positional embedding table ----------------
__global__ __launch_bounds__(256) void pe_k(float* __restrict__ pe) {
    int t = blockIdx.x;
    int i = threadIdx.x;
    float dv  = expf((float)(2 * i) * -0.017988946039015984f);
    float arg = (float)t * dv;
    pe[(size_t)t * DD + 2 * i]     = sinf(arg);
    pe[(size_t)t * DD + 2 * i + 1] = cosf(arg);
}

// ---------------- split fp32 -> 3x bf16 ----------------
__device__ __forceinline__ void cvt3x8(const float* v, bf16x8& q0, bf16x8& q1, bf16x8& q2) {
    #pragma unroll
    for (int j = 0; j < 8; ++j) {
        float f = v[j];
        unsigned short h0 = (unsigned short)((__float_as_uint(f) + 0x8000u) >> 16);
        float f0 = __uint_as_float((unsigned)h0 << 16);
        float r1 = f - f0;
        unsigned short h1 = (unsigned short)((__float_as_uint(r1) + 0x8000u) >> 16);
        float f1 = __uint_as_float((unsigned)h1 << 16);
        float r2 = r1 - f1;
        unsigned short h2 = (unsigned short)((__float_as_uint(r2) + 0x8000u) >> 16);
        q0[j] = (short)h0; q1[j] = (short)h1; q2[j] = (short)h2;
    }
}
__device__ __forceinline__ void cvt3s(float f, short& h0, short& h1, short& h2) {
    unsigned short a0 = (unsigned short)((__float_as_uint(f) + 0x8000u) >> 16);
    float f0 = __uint_as_float((unsigned)a0 << 16);
    float r1 = f - f0;
    unsigned short a1 = (unsigned short)((__float_as_uint(r1) + 0x8000u) >> 16);
    float f1 = __uint_as_float((unsigned)a1 << 16);
    float r2 = r1 - f1;
    unsigned short a2 = (unsigned short)((__float_as_uint(r2) + 0x8000u) >> 16);
    h0 = (short)a0; h1 = (short)a1; h2 = (short)a2;
}

// ---------------- async global->LDS 16B helper ----------------
__device__ __forceinline__ void gld_lds16(const short* src, short* lds) {
    __builtin_amdgcn_global_load_lds(
        (const __attribute__((address_space(1))) unsigned int*)src,
        (__attribute__((address_space(3))) unsigned int*)lds,
        16, 0, 0);
}

// ---------------- weight pre-split: W[K][N] fp32 -> planes [N][K] bf16 x3 ----------------
__global__ __launch_bounds__(256)
void wsplit_tr_k(const float* __restrict__ W, short* __restrict__ P, int N, int K)
{
    const size_t NK = (size_t)N * K;
    const int n = blockIdx.x * 64 + (threadIdx.x & 63);
    #pragma unroll
    for (int it = 0; it < 2; ++it) {
        int k = blockIdx.y * 64 + ((threadIdx.x >> 6) + it * 4) * 8;
        float v[8];
        #pragma unroll
        for (int j = 0; j < 8; ++j) v[j] = W[(size_t)(k + j) * N + n];
        bf16x8 q0, q1, q2;
        cvt3x8(v, q0, q1, q2);
        size_t o = (size_t)n * K + k;
        *(bf16x8*)&P[o] = q0;
        *(bf16x8*)&P[NK + o] = q1;
        *(bf16x8*)&P[2 * NK + o] = q2;
    }
}
// codebook (already [N][K]) direct split
__global__ __launch_bounds__(256)
void wsplit_dir_k(const float* __restrict__ W, short* __restrict__ P, int K, size_t NK)
{
    size_t t = (size_t)blockIdx.x * 256 + threadIdx.x;
    size_t n = t >> 6;
    int k = (int)(t & 63) * 8;
    float v[8];
    *(float4*)&v[0] = *(const float4*)(W + n * K + k);
    *(float4*)&v[4] = *(const float4*)(W + n * K + k + 4);
    bf16x8 q0, q1, q2;
    cvt3x8(v, q0, q1, q2);
    size_t o = n * K + k;
    *(bf16x8*)&P[o] = q0;
    *(bf16x8*)&P[NK + o] = q1;
    *(bf16x8*)&P[2 * NK + o] = q2;
}

// ---------------- MFMA GEMM: BK=64 (two 24KB half-tiles per barrier pair) ----------------
// 4 waves x (32 m x 128 n) = 128x128 tile. Each half keeps the r11-proven
// [plane][n:128][k:32] layout + ((n>>1)&3) chunk swizzle (measured 0 conflicts).
enum { EPI_BIAS = 0, EPI_RES = 1, EPI_RELU = 2, EPI_GELU = 3, EPI_PE = 4, EPI_PLAIN = 5 };

template<int EPI>
__global__ __launch_bounds__(256, 3)
void mgemm2_k(const float* __restrict__ A, const short* __restrict__ Bp,
              const float* __restrict__ bias, const float* __restrict__ extra,
              float* __restrict__ Cv, int Mdim, int Ndim, int Kdim)
{
    __shared__ short Bs[2 * 3 * 4096];   // 48 KB: [half][plane][n:128][k:32]
    const size_t NK = (size_t)Ndim * Kdim;
    const int tid = threadIdx.x;
    const int l   = tid & 63;
    const int w   = tid >> 6;

    int lin = xcd_remap_lin(blockIdx.y * gridDim.x + blockIdx.x, gridDim.x * gridDim.y);
    const int bxx = lin % gridDim.x;
    const int byy = lin / gridDim.x;

    const int wm0 = byy * 128 + w * 32;
    const int bn0 = bxx * 128;
    const int lr  = l & 15;
    const int lk  = (l >> 4) * 8;

    // staging decode: 12 insts (6 per half), each wave writes 1KB/inst
    int sp[12], sn[12], sk[12];
    #pragma unroll
    for (int i = 0; i < 12; ++i) {
        int half = (i >= 6) ? 1 : 0;
        int f = (i - half * 6) * 4096 + tid * 16;
        sp[i] = f >> 13;
        int r = f & 8191;
        sn[i] = r >> 6;
        sk[i] = ((((r & 63) >> 1) ^ (((sn[i] >> 1) & 3) << 3))) + half * 32;
    }

    f32x4 acc[2][8];
    #pragma unroll
    for (int i = 0; i < 2; ++i)
        #pragma unroll
        for (int j = 0; j < 8; ++j)
            acc[i][j] = (f32x4){0.f, 0.f, 0.f, 0.f};

    for (int k0 = 0; k0 < Kdim; k0 += 64) {
        __syncthreads();   // all waves done reading Bs from previous iter
        #pragma unroll
        for (int i = 0; i < 12; ++i) {
            const short* src = Bp + (size_t)sp[i] * NK + (size_t)(bn0 + sn[i]) * Kdim + k0 + sk[i];
            gld_lds16(src, (short*)((char*)Bs + (i >= 6 ? 24576 : 0) + (i - (i >= 6 ? 6 : 0)) * 4096 + w * 1024));
        }

        // A loads for both halves issued early (latency hides under staging)
        float va[2][2][8];
        #pragma unroll
        for (int ss = 0; ss < 2; ++ss)
            #pragma unroll
            for (int mf = 0; mf < 2; ++mf) {
                const float* p = A + (size_t)(wm0 + mf * 16 + lr) * Kdim + k0 + ss * 32 + lk;
                *(float4*)&va[ss][mf][0] = *(const float4*)p;
                *(float4*)&va[ss][mf][4] = *(const float4*)(p + 4);
            }
        __syncthreads();   // staged B visible

        #pragma unroll
        for (int ss = 0; ss < 2; ++ss) {
            bf16x8 a0[2], a1[2], a2[2];
            #pragma unroll
            for (int mf = 0; mf < 2; ++mf)
                cvt3x8(va[ss][mf], a0[mf], a1[mf], a2[mf]);
            const short* Bh = Bs + ss * 12288;
            #pragma unroll
            for (int nf = 0; nf < 8; ++nf) {
                int brow = nf * 16 + lr;
                int lkx = lk ^ (((brow >> 1) & 3) << 3);
                bf16x8 b0 = *(const bf16x8*)&Bh[0 * 4096 + brow * 32 + lkx];
                bf16x8 b1 = *(const bf16x8*)&Bh[1 * 4096 + brow * 32 + lkx];
                bf16x8 b2 = *(const bf16x8*)&Bh[2 * 4096 + brow * 32 + lkx];
                #pragma unroll
                for (int mf = 0; mf < 2; ++mf) {
                    f32x4 c = acc[mf][nf];
                    c = __builtin_amdgcn_mfma_f32_16x16x32_bf16(a0[mf], b0, c, 0, 0, 0);
                    c = __builtin_amdgcn_mfma_f32_16x16x32_bf16(a0[mf], b1, c, 0, 0, 0);
                    c = __builtin_amdgcn_mfma_f32_16x16x32_bf16(a1[mf], b0, c, 0, 0, 0);
                    c = __builtin_amdgcn_mfma_f32_16x16x32_bf16(a1[mf], b1, c, 0, 0, 0);
                    c = __builtin_amdgcn_mfma_f32_16x16x32_bf16(a0[mf], b2, c, 0, 0, 0);
                    c = __builtin_amdgcn_mfma_f32_16x16x32_bf16(a2[mf], b0, c, 0, 0, 0);
                    acc[mf][nf] = c;
                }
            }
        }
    }

    #pragma unroll
    for (int mf = 0; mf < 2; ++mf) {
        #pragma unroll
        for (int r = 0; r < 4; ++r) {
            int m = wm0 + mf * 16 + (l >> 4) * 4 + r;
            #pragma unroll
            for (int nf = 0; nf < 8; ++nf) {
                int n = bn0 + nf * 16 + lr;
                float v = acc[mf][nf][r];
                if constexpr (EPI != EPI_PLAIN) v += bias[n];
                if constexpr (EPI == EPI_RES)  v += extra[(size_t)m * Ndim + n];
                if constexpr (EPI == EPI_PE)   v += extra[(size_t)(m & (TT - 1)) * DD + n];
                if constexpr (EPI == EPI_RELU) v = fmaxf(v, 0.0f);
                if constexpr (EPI == EPI_GELU) v = 0.5f * v * (1.0f + erff(v * 0.70710678118654752f));
                Cv[(size_t)m * Ndim + n] = v;
            }
        }
    }
}

// ---------------- fused VQ dist GEMM (BK=64) + per-block argmin partial ----------------
__global__ __launch_bounds__(256, 3)
void distmin2_k(const float* __restrict__ A, const short* __restrict__ Bp,
                const float* __restrict__ cn2,
                float* __restrict__ pval, int* __restrict__ pidx)
{
    __shared__ short Bs[2 * 3 * 4096];
    const int Ndim = CBB, Kdim = DD;
    const size_t NK = (size_t)Ndim * Kdim;
    const int tid = threadIdx.x;
    const int l   = tid & 63;
    const int w   = tid >> 6;

    int lin = xcd_remap_lin(blockIdx.y * gridDim.x + blockIdx.x, gridDim.x * gridDim.y);
    const int bxx = lin % gridDim.x;
    const int byy = lin / gridDim.x;

    const int wm0 = byy * 128 + w * 32;
    const int bn0 = bxx * 128;
    const int lr  = l & 15;
    const int lk  = (l >> 4) * 8;

    int sp[12], sn[12], sk[12];
    #pragma unroll
    for (int i = 0; i < 12; ++i) {
        int half = (i >= 6) ? 1 : 0;
        int f = (i - half * 6) * 4096 + tid * 16;
        sp[i] = f >> 13;
        int r = f & 8191;
        sn[i] = r >> 6;
        sk[i] = ((((r & 63) >> 1) ^ (((sn[i] >> 1) & 3) << 3))) + half * 32;
    }

    f32x4 acc[2][8];
    #pragma unroll
    for (int i = 0; i < 2; ++i)
        #pragma unroll
        for (int j = 0; j < 8; ++j)
            acc[i][j] = (f32x4){0.f, 0.f, 0.f, 0.f};

    for (int k0 = 0; k0 < Kdim; k0 += 64) {
        __syncthreads();
        #pragma unroll
        for (int i = 0; i < 12; ++i) {
            const short* src = Bp + (size_t)sp[i] * NK + (size_t)(bn0 + sn[i]) * Kdim + k0 + sk[i];
            gld_lds16(src, (short*)((char*)Bs + (i >= 6 ? 24576 : 0) + (i - (i >= 6 ? 6 : 0)) * 4096 + w * 1024));
        }

        float va[2][2][8];
        #pragma unroll
        for (int ss = 0; ss < 2; ++ss)
            #pragma unroll
            for (int mf = 0; mf < 2; ++mf) {
                const float* p = A + (size_t)(wm0 + mf * 16 + lr) * Kdim + k0 + ss * 32 + lk;
                *(float4*)&va[ss][mf][0] = *(const float4*)p;
                *(float4*)&va[ss][mf][4] = *(const float4*)(p + 4);
            }
        __syncthreads();

        #pragma unroll
        for (int ss = 0; ss < 2; ++ss) {
            bf16x8 a0[2], a1[2], a2[2];
            #pragma unroll
            for (int mf = 0; mf < 2; ++mf)
                cvt3x8(va[ss][mf], a0[mf], a1[mf], a2[mf]);
            const short* Bh = Bs + ss * 12288;
            #pragma unroll
            for (int nf = 0; nf < 8; ++nf) {
                int brow = nf * 16 + lr;
                int lkx = lk ^ (((brow >> 1) & 3) << 3);
                bf16x8 b0 = *(const bf16x8*)&Bh[0 * 4096 + brow * 32 + lkx];
                bf16x8 b1 = *(const bf16x8*)&Bh[1 * 4096 + brow * 32 + lkx];
                bf16x8 b2 = *(const bf16x8*)&Bh[2 * 4096 + brow * 32 + lkx];
                #pragma unroll
                for (int mf = 0; mf < 2; ++mf) {
                    f32x4 c = acc[mf][nf];
                    c = __builtin_amdgcn_mfma_f32_16x16x32_bf16(a0[mf], b0, c, 0, 0, 0);
                    c = __builtin_amdgcn_mfma_f32_16x16x32_bf16(a0[mf], b1, c, 0, 0, 0);
                    c = __builtin_amdgcn_mfma_f32_16x16x32_bf16(a1[mf], b0, c, 0, 0, 0);
                    c = __builtin_amdgcn_mfma_f32_16x16x32_bf16(a1[mf], b1, c, 0, 0, 0);
                    c = __builtin_amdgcn_mfma_f32_16x16x32_bf16(a0[mf], b2, c, 0, 0, 0);
                    c = __builtin_amdgcn_mfma_f32_16x16x32_bf16(a2[mf], b0, c, 0, 0, 0);
                    acc[mf][nf] = c;
                }
            }
        }
    }

    // fused argmin epilogue (ascending-n strict <, lane-reduce lower-idx tie-break)
    #pragma unroll
    for (int mf = 0; mf < 2; ++mf) {
        #pragma unroll
        for (int r = 0; r < 4; ++r) {
            int m = wm0 + mf * 16 + (l >> 4) * 4 + r;
            float best = INFINITY; int bi = 0x7fffffff;
            #pragma unroll
            for (int nf = 0; nf < 8; ++nf) {
                int n = bn0 + nf * 16 + lr;
                float d = cn2[n] - 2.0f * acc[mf][nf][r];
                if (d < best) { best = d; bi = n; }
            }
            #pragma unroll
            for (int off = 1; off < 16; off <<= 1) {
                float ov = __shfl_xor(best, off);
                int   oi = __shfl_xor(bi, off);
                if (ov < best || (ov == best && oi < bi)) { best = ov; bi = oi; }
            }
            if (lr == 0) {
                pval[(size_t)m * 8 + bxx] = best;
                pidx[(size_t)m * 8 + bxx] = bi;
            }
        }
    }
}

// ---------------- combine 8 per-block argmin partials ----------------
__global__ __launch_bounds__(256)
void argmin8_k(const float* __restrict__ pval, const int* __restrict__ pidx,
               int* __restrict__ idx)
{
    int row = blockIdx.x * 256 + threadIdx.x;
    float best = INFINITY; int bi = 0x7fffffff;
    #pragma unroll
    for (int j = 0; j < 8; ++j) {
        float v = pval[(size_t)row * 8 + j];
        int  ii = pidx[(size_t)row * 8 + j];
        if (v < best || (v == best && ii < bi)) { best = v; bi = ii; }
    }
    idx[row] = bi;
}

// ---------------- MFMA flash attention (LDS-staged from f32 qkv) ----------------
__global__ __launch_bounds__(256, 2)
void mattn_k(const float* __restrict__ qkv, float* __restrict__ o)
{
    const int bid = xcd_remap_lin(blockIdx.x, gridDim.x);
    const int qt = bid & 7;
    const int hh = (bid >> 3) & 7;
    const int bb = bid >> 6;
    const int tid = threadIdx.x;
    const int w  = tid >> 6;
    const int l  = tid & 63;
    const int lr = l & 15;
    const int lg = l >> 4;
    const int lk = lg * 8;

    __shared__ short Kb[3][4096];
    __shared__ short Vb[3][4096];
    __shared__ float Ps[4][1024];

    const float* qbase = qkv + (size_t)bb * TT * 1536 + hh * 64;
    const float* kbase = qbase + DD;
    const float* vbase = qbase + 2 * DD;

    bf16x8 qa[2][3];
    {
        int qrow = qt * 64 + w * 16 + lr;
        #pragma unroll
        for (int dc = 0; dc < 2; ++dc) {
            float v[8];
            const float* p = qbase + (size_t)qrow * 1536 + dc * 32 + lk;
            *(float4*)&v[0] = *(const float4*)p;
            *(float4*)&v[4] = *(const float4*)(p + 4);
            cvt3x8(v, qa[dc][0], qa[dc][1], qa[dc][2]);
        }
    }

    f32x4 oacc[4];
    #pragma unroll
    for (int nf = 0; nf < 4; ++nf) oacc[nf] = (f32x4){0.f, 0.f, 0.f, 0.f};
    float m[4], s[4];
    #pragma unroll
    for (int r = 0; r < 4; ++r) { m[r] = -INFINITY; s[r] = 0.f; }

    for (int kt = 0; kt <= qt; ++kt) {
        __syncthreads();
        {
            int kr = tid >> 2, dseg = (tid & 3) * 16;
            const float* p = kbase + (size_t)(kt * 64 + kr) * 1536 + dseg;
            float v[16];
            *(float4*)&v[0]  = *(const float4*)p;
            *(float4*)&v[4]  = *(const float4*)(p + 4);
            *(float4*)&v[8]  = *(const float4*)(p + 8);
            *(float4*)&v[12] = *(const float4*)(p + 12);
            bf16x8 t0, t1, t2, u0, u1, u2;
            cvt3x8(v, t0, t1, t2);
            cvt3x8(v + 8, u0, u1, u2);
            int si = (kr * 64 + dseg) ^ ((kr & 7) << 3);
            *(bf16x8*)&Kb[0][si] = t0; *(bf16x8*)&Kb[0][si ^ 8] = u0;
            *(bf16x8*)&Kb[1][si] = t1; *(bf16x8*)&Kb[1][si ^ 8] = u1;
            *(bf16x8*)&Kb[2][si] = t2; *(bf16x8*)&Kb[2][si ^ 8] = u2;
        }
        {
            int d = tid & 63, kg = (tid >> 6) * 16;
            const float* p = vbase + (size_t)(kt * 64 + kg) * 1536 + d;
            bf16x8 w0[2], w1[2], w2[2];
            #pragma unroll
            for (int i = 0; i < 16; ++i) {
                float f = p[(size_t)i * 1536];
                short h0, h1, h2; cvt3s(f, h0, h1, h2);
                w0[i >> 3][i & 7] = h0; w1[i >> 3][i & 7] = h1; w2[i >> 3][i & 7] = h2;
            }
            int si = (d * 64 + kg) ^ ((d & 7) << 3);
            *(bf16x8*)&Vb[0][si] = w0[0]; *(bf16x8*)&Vb[0][si ^ 8] = w0[1];
            *(bf16x8*)&Vb[1][si] = w1[0]; *(bf16x8*)&Vb[1][si ^ 8] = w1[1];
            *(bf16x8*)&Vb[2][si] = w2[0]; *(bf16x8*)&Vb[2][si ^ 8] = w2[1];
        }
        __syncthreads();

        f32x4 S4[4];
        #pragma unroll
        for (int nf = 0; nf < 4; ++nf) {
            f32x4 acc = (f32x4){0.f, 0.f, 0.f, 0.f};
            int kcol = nf * 16 + lr;
            int rowx = kcol * 64, sw = (kcol & 7) << 3;
            #pragma unroll
            for (int dc = 0; dc < 2; ++dc) {
                int si = rowx + ((dc * 32 + lk) ^ sw);
                bf16x8 b0 = *(const bf16x8*)&Kb[0][si];
                bf16x8 b1 = *(const bf16x8*)&Kb[1][si];
                bf16x8 b2 = *(const bf16x8*)&Kb[2][si];
                acc = __builtin_amdgcn_mfma_f32_16x16x32_bf16(qa[dc][0], b0, acc, 0, 0, 0);
                acc = __builtin_amdgcn_mfma_f32_16x16x32_bf16(qa[dc][0], b1, acc, 0, 0, 0);
                acc = __builtin_amdgcn_mfma_f32_16x16x32_bf16(qa[dc][1], b0, acc, 0, 0, 0);
                acc = __builtin_amdgcn_mfma_f32_16x16x32_bf16(qa[dc][1], b1, acc, 0, 0, 0);
                acc = __builtin_amdgcn_mfma_f32_16x16x32_bf16(qa[dc][0], b2, acc, 0, 0, 0);
                acc = __builtin_amdgcn_mfma_f32_16x16x32_bf16(qa[dc][2], b0, acc, 0, 0, 0);
            }
            S4[nf] = acc;
        }
        #pragma unroll
        for (int nf = 0; nf < 4; ++nf)
            #pragma unroll
            for (int r = 0; r < 4; ++r) S4[nf][r] *= 0.125f;
        if (kt == qt) {
            #pragma unroll
            for (int nf = 0; nf < 4; ++nf) {
                int kg_ = nf * 16 + lr;
                #pragma unroll
                for (int r = 0; r < 4; ++r) {
                    int qg_ = w * 16 + lg * 4 + r;
                    if (kg_ > qg_) S4[nf][r] = -INFINITY;
                }
            }
        }
        float mnew[4], scl[4], psum[4];
        #pragma unroll
        for (int r = 0; r < 4; ++r) {
            float v = fmaxf(fmaxf(S4[0][r], S4[1][r]), fmaxf(S4[2][r], S4[3][r]));
            v = fmaxf(v, __shfl_xor(v, 1));
            v = fmaxf(v, __shfl_xor(v, 2));
            v = fmaxf(v, __shfl_xor(v, 4));
            v = fmaxf(v, __shfl_xor(v, 8));
            mnew[r] = fmaxf(m[r], v);
            scl[r] = expf(m[r] - mnew[r]);
            psum[r] = 0.f;
        }
        #pragma unroll
        for (int nf = 0; nf < 4; ++nf) {
            #pragma unroll
            for (int r = 0; r < 4; ++r) {
                float p = expf(S4[nf][r] - mnew[r]);
                int row = lg * 4 + r;
                int col = nf * 16 + lr;
                Ps[w][row * 64 + (col ^ ((row & 7) << 3))] = p;
                psum[r] += p;
            }
        }
        #pragma unroll
        for (int r = 0; r < 4; ++r) {
            float v = psum[r];
            v += __shfl_xor(v, 1);
            v += __shfl_xor(v, 2);
            v += __shfl_xor(v, 4);
            v += __shfl_xor(v, 8);
            s[r] = s[r] * scl[r] + v;
            m[r] = mnew[r];
        }
        #pragma unroll
        for (int nf = 0; nf < 4; ++nf)
            #pragma unroll
            for (int r = 0; r < 4; ++r) oacc[nf][r] *= scl[r];

        #pragma unroll
        for (int kc = 0; kc < 2; ++kc) {
            int fi = lr * 64 + ((kc * 32 + lk) ^ ((lr & 7) << 3));
            float pv8[8];
            *(float4*)&pv8[0] = *(const float4*)&Ps[w][fi];
            *(float4*)&pv8[4] = *(const float4*)&Ps[w][fi + 4];
            bf16x8 pa0, pa1, pa2;
            cvt3x8(pv8, pa0, pa1, pa2);
            #pragma unroll
            for (int nf = 0; nf < 4; ++nf) {
                int drow = nf * 16 + lr;
                int si = drow * 64 + ((kc * 32 + lk) ^ ((drow & 7) << 3));
                bf16x8 b0 = *(const bf16x8*)&Vb[0][si];
                bf16x8 b1 = *(const bf16x8*)&Vb[1][si];
                bf16x8 b2 = *(const bf16x8*)&Vb[2][si];
                f32x4 c = oacc[nf];
                c = __builtin_amdgcn_mfma_f32_16x16x32_bf16(pa0, b0, c, 0, 0, 0);
                c = __builtin_amdgcn_mfma_f32_16x16x32_bf16(pa0, b1, c, 0, 0, 0);
                c = __builtin_amdgcn_mfma_f32_16x16x32_bf16(pa1, b0, c, 0, 0, 0);
                c = __builtin_amdgcn_mfma_f32_16x16x32_bf16(pa1, b1, c, 0, 0, 0);
                c = __builtin_amdgcn_mfma_f32_16x16x32_bf16(pa0, b2, c, 0, 0, 0);
                c = __builtin_amdgcn_mfma_f32_16x16x32_bf16(pa2, b0, c, 0, 0, 0);
                oacc[nf] = c;
            }
        }
    }

    #pragma unroll
    for (int nf = 0; nf < 4; ++nf) {
        #pragma unroll
        for (int r = 0; r < 4; ++r) {
            int qrow = qt * 64 + w * 16 + lg * 4 + r;
            o[(size_t)(bb * TT + qrow) * DD + hh * 64 + nf * 16 + lr] = oacc[nf][r] / s[r];
        }
    }
}

// ---------------- layernorm ----------------
__global__ __launch_bounds__(256)
void ln_k(const float* __restrict__ src, const float* __restrict__ s,
          const float* __restrict__ b, float* __restrict__ dst)
{
    __shared__ float red[256];
    const int row = blockIdx.x, t = threadIdx.x;
    const size_t base = (size_t)row * DD;
    float x0 = src[base + t], x1 = src[base + 256 + t];
    float mean = blk_reduce(x0 + x1, red) * (1.0f / 512.0f);
    float d0 = x0 - mean, d1 = x1 - mean;
    float var = blk_reduce(d0 * d0 + d1 * d1, red) * (1.0f / 512.0f);
    float inv = 1.0f / sqrtf(var + 1e-5f);
    dst[base + t]       = d0 * inv * s[t] + b[t];
    dst[base + 256 + t] = d1 * inv * s[t + 256] + b[t + 256];
}

// ---------------- codebook squared norms ----------------
__global__ __launch_bounds__(256)
void cn2_k(const float* __restrict__ cb, float* __restrict__ cn2)
{
    __shared__ float red[256];
    const int row = blockIdx.x, t = threadIdx.x;
    float a = cb[(size_t)row * DD + t], b = cb[(size_t)row * DD + 256 + t];
    float tot = blk_reduce(a * a + b * b, red);
    if (t == 0) cn2[row] = tot;
}

// ---------------- rotation trick + residual update + loss partial ----------------
__global__ __launch_bounds__(256)
void rotate_k(float* __restrict__ r, const float* __restrict__ cb,
              const int* __restrict__ idx, float* __restrict__ qo,
              float* __restrict__ lp)
{
    __shared__ float red[256];
    const int row = blockIdx.x, t = threadIdx.x;
    const size_t base = (size_t)row * DD;
    const float* qv = cb + (size_t)idx[row] * DD;
    float x0 = r[base + t], x1 = r[base + 256 + t];
    float q0 = qv[t], q1 = qv[t + 256];
    float nx2 = blk_reduce(x0 * x0 + x1 * x1, red);
    float nq2 = blk_reduce(q0 * q0 + q1 * q1, red);
    float dl0 = q0 - x0, dl1 = q1 - x1;
    float ls = blk_reduce(dl0 * dl0 + dl1 * dl1, red);
    if (t == 0) lp[row] = ls;
    const float eps = 1e-6f;
    float nx = sqrtf(nx2), nq = sqrtf(nq2);
    float mx = fmaxf(nx, eps), mq = fmaxf(nq, eps);
    float u0 = x0 / mx, u1 = x1 / mx;
    float qn0 = q0 / mq, qn1 = q1 / mq;
    float w0 = u0 + qn0, w1 = u1 + qn1;
    float nw2 = blk_reduce(w0 * w0 + w1 * w1, red);
    float mw = fmaxf(sqrtf(nw2), eps);
    w0 /= mw; w1 /= mw;
    float xw = blk_reduce(x0 * w0 + x1 * w1, red);
    float xu = blk_reduce(x0 * u0 + x1 * u1, red);
    float scl = nq / mx;
    float o0 = (x0 - 2.0f * xw * w0 + 2.0f * xu * qn0) * scl;
    float o1 = (x1 - 2.0f * xw * w1 + 2.0f * xu * qn1) * scl;
    r[base + t]        = x0 - o0;
    r[base + 256 + t]  = x1 - o1;
    qo[base + t]       += o0;
    qo[base + 256 + t] += o1;
}

// ---------------- commit loss reduce (f32 out) ----------------
__global__ __launch_bounds__(256)
void loss_k(const float* __restrict__ lp, float* __restrict__ out)
{
    __shared__ float red[256];
    const int t = threadIdx.x;
    float cm = 0.f;
    for (int qi = 0; qi < NQQ; ++qi) {
        float s = 0.f;
        for (int i = t; i < MM; i += 256) s += lp[qi * MM + i];
        float tot = blk_reduce(s, red);
        cm += 0.25f * (tot / (float)(MM * DD));
    }
    if (t == 0) out[0] = cm / (float)NQQ;
}

// ---------------- indices -> f32 output ----------------
__global__ __launch_bounds__(256)
void idxout_k(const int* __restrict__ idxw, float* __restrict__ out)
{
    int i = blockIdx.x * 256 + threadIdx.x;
    int row = i >> 2, qi = i & 3;
    out[i] = (float)idxw[qi * MM + row];
}

// ---------------- host launch ----------------
extern "C" void kernel_launch(void* const* d_in, const int* in_sizes, int n_in,
                              void* d_out, int out_size, void* d_ws, size_t ws_size,
                              hipStream_t stream)
{
    const float* x     = (const float*)d_in[0];
    const float* w_in  = (const float*)d_in[1];
    const float* b_in  = (const float*)d_in[2];
    const float* qkv_w = (const float*)d_in[3];
    const float* qkv_b = (const float*)d_in[4];
    const float* out_w = (const float*)d_in[5];
    const float* out_b = (const float*)d_in[6];
    const float* ln1_s = (const float*)d_in[7];
    const float* ln1_b = (const float*)d_in[8];
    const float* ln2_s = (const float*)d_in[9];
    const float* ln2_b = (const float*)d_in[10];
    const float* ff1_w = (const float*)d_in[11];
    const float* ff1_b = (const float*)d_in[12];
    const float* ff2_w = (const float*)d_in[13];
    const float* ff2_b = (const float*)d_in[14];
    const float* cbs   = (const float*)d_in[15];
    const float* dln_s = (const float*)d_in[16];
    const float* dln_b = (const float*)d_in[17];
    const float* dw1   = (const float*)d_in[18];
    const float* db1   = (const float*)d_in[19];
    const float* dw2   = (const float*)d_in[20];
    const float* db2   = (const float*)d_in[21];

    // ---- workspace: fixed 87.6 MB + chunk scratch ----
    float* ws  = (float*)d_ws;
    float* pe  = ws;                                   //   262,144 f
    float* h   = pe + (size_t)262144;                  // 8,388,608 f
    float* h2  = h + (size_t)MM * DD;                  // 8,388,608 f
    float* cn2 = h2 + (size_t)MM * DD;                 //     4,096 f
    float* lp  = cn2 + 4096;                           //    65,536 f
    int*   idxw = (int*)(lp + 65536);                  //    65,536 i
    short* wp  = (short*)(idxw + 65536);               // 9,437,184 shorts (18 MB shared planes)

    short* p_qkv = wp;                                  // 2,359,296
    short* p_out = wp + (size_t)2359296;                //   786,432
    short* p_ff1 = wp + (size_t)3145728;                // 3,145,728
    short* p_ff2 = wp + (size_t)6291456;                // 3,145,728
    short* p_win = wp;                                  //   393,216 (reuse, pre-loop)
    short* p_cb  = wp;                                  // 1,572,864 (reuse, VQ phase)
    short* p_dw1 = wp;                                  //   786,432 (reuse, decoder)
    short* p_dw2 = wp + (size_t)786432;                 //   393,216
    float* C = (float*)(wp + (size_t)9437184);

    size_t fixed_bytes = (size_t)((char*)C - (char*)ws);
    size_t cbytes = (ws_size > fixed_bytes) ? ws_size - fixed_bytes : 0;
    int CH = 32;
    while (CH > 1 && (size_t)CH * TT * 2048 * sizeof(float) > cbytes) CH >>= 1;
    const int NC = BB / CH;
    const int CR = CH * TT;

    float* qkvc  = C;                          // [CR][1536]
    float* attoc = C + (size_t)CR * 1536;      // [CR][512]
    float* midc  = C;                          // [CR][2048]
    float* pval  = C;                          // [CR][8] f (VQ partial vals)
    int*   pidx  = (int*)(C + (size_t)CR * 8); // [CR][8] i (VQ partial idx)
    float* dhc   = C;                          // [CR][512]
    float* dmidc = C + (size_t)CR * DD;        // [CR][512]

    // ---- prologue ----
    pe_k<<<dim3(512), dim3(256), 0, stream>>>(pe);
    cn2_k<<<dim3(NQQ * CBB), 256, 0, stream>>>(cbs, cn2);
    wsplit_tr_k<<<dim3(8, 4), 256, 0, stream>>>(w_in, p_win, 512, 256);
    mgemm2_k<EPI_PE><<<dim3(4, 128), 256, 0, stream>>>(x, p_win, b_in, pe, h, MM, DD, 256);

    for (int l = 0; l < NLL; ++l) {
        wsplit_tr_k<<<dim3(24, 8), 256, 0, stream>>>(qkv_w + (size_t)l * DD * 1536, p_qkv, 1536, 512);
        wsplit_tr_k<<<dim3(8, 8), 256, 0, stream>>>(out_w + (size_t)l * DD * DD, p_out, 512, 512);
        wsplit_tr_k<<<dim3(32, 8), 256, 0, stream>>>(ff1_w + (size_t)l * DD * 2048, p_ff1, 2048, 512);
        wsplit_tr_k<<<dim3(8, 32), 256, 0, stream>>>(ff2_w + (size_t)l * 2048 * DD, p_ff2, 512, 2048);
        for (int c = 0; c < NC; ++c) {
            float* hc  = h  + (size_t)c * CR * DD;
            float* h2c = h2 + (size_t)c * CR * DD;
            mgemm2_k<EPI_BIAS><<<dim3(12, CR / 128), 256, 0, stream>>>(
                hc, p_qkv, qkv_b + (size_t)l * 1536, nullptr, qkvc, CR, 1536, DD);
            mattn_k<<<dim3(CH * 64), 256, 0, stream>>>(qkvc, attoc);
            mgemm2_k<EPI_RES><<<dim3(4, CR / 128), 256, 0, stream>>>(
                attoc, p_out, out_b + (size_t)l * DD, hc, h2c, CR, DD, DD);
            ln_k<<<dim3(CR), 256, 0, stream>>>(h2c, ln1_s + (size_t)l * DD, ln1_b + (size_t)l * DD, h2c);
            mgemm2_k<EPI_RELU><<<dim3(16, CR / 128), 256, 0, stream>>>(
                h2c, p_ff1, ff1_b + (size_t)l * 2048, nullptr, midc, CR, 2048, DD);
            mgemm2_k<EPI_RES><<<dim3(4, CR / 128), 256, 0, stream>>>(
                midc, p_ff2, ff2_b + (size_t)l * DD, h2c, hc, CR, DD, 2048);
            ln_k<<<dim3(CR), 256, 0, stream>>>(hc, ln2_s + (size_t)l * DD, ln2_b + (size_t)l * DD, hc);
        }
    }

    // ---- residual VQ: fused dist GEMM + argmin partials, combine, rotate ----
    hipMemsetAsync(h2, 0, (size_t)MM * DD * sizeof(float), stream);
    for (int qi = 0; qi < NQQ; ++qi) {
        wsplit_dir_k<<<dim3(256), 256, 0, stream>>>(cbs + (size_t)qi * CBB * DD, p_cb, 512, 524288);
        for (int c = 0; c < NC; ++c) {
            float* hc = h + (size_t)c * CR * DD;
            distmin2_k<<<dim3(8, CR / 128), 256, 0, stream>>>(
                hc, p_cb, cn2 + qi * CBB, pval, pidx);
            argmin8_k<<<dim3(CR / 256), 256, 0, stream>>>(pval, pidx,
                                                          idxw + qi * MM + (size_t)c * CR);
        }
        rotate_k<<<dim3(MM), 256, 0, stream>>>(h, cbs + (size_t)qi * CBB * DD,
                                               idxw + qi * MM, h2, lp + qi * MM);
    }

    float* outf = (float*)d_out;
    loss_k<<<dim3(1), 256, 0, stream>>>(lp, outf + (size_t)MM * DATA);
    idxout_k<<<dim3(256), 256, 0, stream>>>(idxw, outf + (size_t)MM * DATA + 1);

    // ---- decoder ----
    wsplit_tr_k<<<dim3(8, 8), 256, 0, stream>>>(dw1, p_dw1, 512, 512);
    wsplit_tr_k<<<dim3(4, 8), 256, 0, stream>>>(dw2, p_dw2, 256, 512);
    for (int c = 0; c < NC; ++c) {
        float* h2c = h2 + (size_t)c * CR * DD;
        ln_k<<<dim3(CR), 256, 0, stream>>>(h2c, dln_s, dln_b, dhc);
        mgemm2_k<EPI_GELU><<<dim3(4, CR / 128), 256, 0, stream>>>(
            dhc, p_dw1, db1, nullptr, dmidc, CR, DD, DD);
        mgemm2_k<EPI_BIAS><<<dim3(2, CR / 128), 256, 0, stream>>>(
            dmidc, p_dw2, db2, nullptr, outf + (size_t)c * CR * DATA, CR, DATA, DD);
    }
}

// Round 17
// 3499.336 us; speedup vs baseline: 1.0308x; 1.0308x over previous
//
#include <hip/hip_runtime.h>
#include <hip/hip_bf16.h>
#include <math.h>

#define DD   512
#define NHH  8
#define DHH  64
#define NLL  4
#define NQQ  4
#define CBB  1024
#define DATA 256
#define BB   32
#define TT   512
#define MM   (BB*TT)   // 16384

typedef __attribute__((ext_vector_type(8))) short bf16x8;
typedef __attribute__((ext_vector_type(4))) float f32x4;

// ---------------- block reduce ----------------
__device__ __forceinline__ float blk_reduce(float v, float* red) {
    const int t = threadIdx.x;
    red[t] = v;
    __syncthreads();
    #pragma unroll
    for (int s = 128; s > 0; s >>= 1) {
        if (t < s) red[t] += red[t + s];
        __syncthreads();
    }
    float r = red[0];
    __syncthreads();
    return r;
}

// ---------------- XCD-aware bijective block remap (m204) ----------------
__device__ __forceinline__ int xcd_remap_lin(int orig, int nwg) {
    int xcd = orig & 7;
    int q = nwg >> 3, r = nwg & 7;
    int base = (xcd < r) ? xcd * (q + 1) : r * (q + 1) + (xcd - r) * q;
    return base + (orig >> 3);
}

// ---------------- positional embedding table ----------------
__global__ __launch_bounds__(256) void pe_k(float* __restrict__ pe) {
    int t = blockIdx.x;
    int i = threadIdx.x;
    float dv  = expf((float)(2 * i) * -0.017988946039015984f);
    float arg = (float)t * dv;
    pe[(size_t)t * DD + 2 * i]     = sinf(arg);
    pe[(size_t)t * DD + 2 * i + 1] = cosf(arg);
}

// ---------------- split fp32 -> 3x bf16 ----------------
__device__ __forceinline__ void cvt3x8(const float* v, bf16x8& q0, bf16x8& q1, bf16x8& q2) {
    #pragma unroll
    for (int j = 0; j < 8; ++j) {
        float f = v[j];
        unsigned short h0 = (unsigned short)((__float_as_uint(f) + 0x8000u) >> 16);
        float f0 = __uint_as_float((unsigned)h0 << 16);
        float r1 = f - f0;
        unsigned short h1 = (unsigned short)((__float_as_uint(r1) + 0x8000u) >> 16);
        float f1 = __uint_as_float((unsigned)h1 << 16);
        float r2 = r1 - f1;
        unsigned short h2 = (unsigned short)((__float_as_uint(r2) + 0x8000u) >> 16);
        q0[j] = (short)h0; q1[j] = (short)h1; q2[j] = (short)h2;
    }
}
__device__ __forceinline__ void cvt3s(float f, short& h0, short& h1, short& h2) {
    unsigned short a0 = (unsigned short)((__float_as_uint(f) + 0x8000u) >> 16);
    float f0 = __uint_as_float((unsigned)a0 << 16);
    float r1 = f - f0;
    unsigned short a1 = (unsigned short)((__float_as_uint(r1) + 0x8000u) >> 16);
    float f1 = __uint_as_float((unsigned)a1 << 16);
    float r2 = r1 - f1;
    unsigned short a2 = (unsigned short)((__float_as_uint(r2) + 0x8000u) >> 16);
    h0 = (short)a0; h1 = (short)a1; h2 = (short)a2;
}

// ---------------- async global->LDS 16B helper ----------------
__device__ __forceinline__ void gld_lds16(const short* src, short* lds) {
    __builtin_amdgcn_global_load_lds(
        (const __attribute__((address_space(1))) unsigned int*)src,
        (__attribute__((address_space(3))) unsigned int*)lds,
        16, 0, 0);
}

// ---------------- weight pre-split: W[K][N] fp32 -> planes [N][K] bf16 x3 ----------------
__global__ __launch_bounds__(256)
void wsplit_tr_k(const float* __restrict__ W, short* __restrict__ P, int N, int K)
{
    const size_t NK = (size_t)N * K;
    const int n = blockIdx.x * 64 + (threadIdx.x & 63);
    #pragma unroll
    for (int it = 0; it < 2; ++it) {
        int k = blockIdx.y * 64 + ((threadIdx.x >> 6) + it * 4) * 8;
        float v[8];
        #pragma unroll
        for (int j = 0; j < 8; ++j) v[j] = W[(size_t)(k + j) * N + n];
        bf16x8 q0, q1, q2;
        cvt3x8(v, q0, q1, q2);
        size_t o = (size_t)n * K + k;
        *(bf16x8*)&P[o] = q0;
        *(bf16x8*)&P[NK + o] = q1;
        *(bf16x8*)&P[2 * NK + o] = q2;
    }
}
// codebook (already [N][K]) direct split
__global__ __launch_bounds__(256)
void wsplit_dir_k(const float* __restrict__ W, short* __restrict__ P, int K, size_t NK)
{
    size_t t = (size_t)blockIdx.x * 256 + threadIdx.x;
    size_t n = t >> 6;
    int k = (int)(t & 63) * 8;
    float v[8];
    *(float4*)&v[0] = *(const float4*)(W + n * K + k);
    *(float4*)&v[4] = *(const float4*)(W + n * K + k + 4);
    bf16x8 q0, q1, q2;
    cvt3x8(v, q0, q1, q2);
    size_t o = n * K + k;
    *(bf16x8*)&P[o] = q0;
    *(bf16x8*)&P[NK + o] = q1;
    *(bf16x8*)&P[2 * NK + o] = q2;
}

// ---------------- MFMA GEMM: BK=32, double-buffered staging, 1 barrier/k-step ----------------
// 4 waves x (32 m x 128 n) = 128x128 tile; r11-proven layout + ((n>>1)&3) swizzle.
// T3 minimum 2-phase: stage(buf^1, t+1) BEFORE compute(buf); one barrier per tile.
enum { EPI_BIAS = 0, EPI_RES = 1, EPI_RELU = 2, EPI_GELU = 3, EPI_PE = 4, EPI_PLAIN = 5 };

template<int EPI>
__global__ __launch_bounds__(256, 3)
void mgemm2_k(const float* __restrict__ A, const short* __restrict__ Bp,
              const float* __restrict__ bias, const float* __restrict__ extra,
              float* __restrict__ Cv, int Mdim, int Ndim, int Kdim)
{
    __shared__ short Bs[2][3 * 4096];   // 48 KB: [buf][plane][n:128][k:32]
    const size_t NK = (size_t)Ndim * Kdim;
    const int tid = threadIdx.x;
    const int l   = tid & 63;
    const int w   = tid >> 6;

    int lin = xcd_remap_lin(blockIdx.y * gridDim.x + blockIdx.x, gridDim.x * gridDim.y);
    const int bxx = lin % gridDim.x;
    const int byy = lin / gridDim.x;

    const int wm0 = byy * 128 + w * 32;
    const int bn0 = bxx * 128;
    const int lr  = l & 15;
    const int lk  = (l >> 4) * 8;

    int sp[6], sn[6], sk[6];
    #pragma unroll
    for (int i = 0; i < 6; ++i) {
        int f = i * 4096 + tid * 16;
        sp[i] = f >> 13;
        int r = f & 8191;
        sn[i] = r >> 6;
        sk[i] = ((r & 63) >> 1) ^ (((sn[i] >> 1) & 3) << 3);
    }

    f32x4 acc[2][8];
    #pragma unroll
    for (int i = 0; i < 2; ++i)
        #pragma unroll
        for (int j = 0; j < 8; ++j)
            acc[i][j] = (f32x4){0.f, 0.f, 0.f, 0.f};

    // prologue: stage k0=0 into buf 0, drain once
    #pragma unroll
    for (int i = 0; i < 6; ++i) {
        const short* src = Bp + (size_t)sp[i] * NK + (size_t)(bn0 + sn[i]) * Kdim + sk[i];
        gld_lds16(src, (short*)((char*)&Bs[0][0] + i * 4096 + w * 1024));
    }
    __syncthreads();

    int cur = 0;
    for (int k0 = 0; k0 < Kdim; k0 += 32) {
        // issue next tile's staging early (latency hides under compute)
        if (k0 + 32 < Kdim) {
            #pragma unroll
            for (int i = 0; i < 6; ++i) {
                const short* src = Bp + (size_t)sp[i] * NK + (size_t)(bn0 + sn[i]) * Kdim + (k0 + 32) + sk[i];
                gld_lds16(src, (short*)((char*)&Bs[cur ^ 1][0] + i * 4096 + w * 1024));
            }
        }

        bf16x8 a0[2], a1[2], a2[2];
        #pragma unroll
        for (int mf = 0; mf < 2; ++mf) {
            const float* p = A + (size_t)(wm0 + mf * 16 + lr) * Kdim + k0 + lk;
            float v[8];
            *(float4*)&v[0] = *(const float4*)p;
            *(float4*)&v[4] = *(const float4*)(p + 4);
            cvt3x8(v, a0[mf], a1[mf], a2[mf]);
        }

        const short* Bh = &Bs[cur][0];
        #pragma unroll
        for (int nf = 0; nf < 8; ++nf) {
            int brow = nf * 16 + lr;
            int lkx = lk ^ (((brow >> 1) & 3) << 3);
            bf16x8 b0 = *(const bf16x8*)&Bh[0 * 4096 + brow * 32 + lkx];
            bf16x8 b1 = *(const bf16x8*)&Bh[1 * 4096 + brow * 32 + lkx];
            bf16x8 b2 = *(const bf16x8*)&Bh[2 * 4096 + brow * 32 + lkx];
            #pragma unroll
            for (int mf = 0; mf < 2; ++mf) {
                f32x4 c = acc[mf][nf];
                c = __builtin_amdgcn_mfma_f32_16x16x32_bf16(a0[mf], b0, c, 0, 0, 0);
                c = __builtin_amdgcn_mfma_f32_16x16x32_bf16(a0[mf], b1, c, 0, 0, 0);
                c = __builtin_amdgcn_mfma_f32_16x16x32_bf16(a1[mf], b0, c, 0, 0, 0);
                c = __builtin_amdgcn_mfma_f32_16x16x32_bf16(a1[mf], b1, c, 0, 0, 0);
                c = __builtin_amdgcn_mfma_f32_16x16x32_bf16(a0[mf], b2, c, 0, 0, 0);
                c = __builtin_amdgcn_mfma_f32_16x16x32_bf16(a2[mf], b0, c, 0, 0, 0);
                acc[mf][nf] = c;
            }
        }
        __syncthreads();   // releases Bs[cur] for overwrite; drains prefetch for Bs[cur^1]
        cur ^= 1;
    }

    #pragma unroll
    for (int mf = 0; mf < 2; ++mf) {
        #pragma unroll
        for (int r = 0; r < 4; ++r) {
            int m = wm0 + mf * 16 + (l >> 4) * 4 + r;
            #pragma unroll
            for (int nf = 0; nf < 8; ++nf) {
                int n = bn0 + nf * 16 + lr;
                float v = acc[mf][nf][r];
                if constexpr (EPI != EPI_PLAIN) v += bias[n];
                if constexpr (EPI == EPI_RES)  v += extra[(size_t)m * Ndim + n];
                if constexpr (EPI == EPI_PE)   v += extra[(size_t)(m & (TT - 1)) * DD + n];
                if constexpr (EPI == EPI_RELU) v = fmaxf(v, 0.0f);
                if constexpr (EPI == EPI_GELU) v = 0.5f * v * (1.0f + erff(v * 0.70710678118654752f));
                Cv[(size_t)m * Ndim + n] = v;
            }
        }
    }
}

// ---------------- fused VQ dist GEMM (dbuf BK=32) + per-block argmin partial ----------------
__global__ __launch_bounds__(256, 3)
void distmin2_k(const float* __restrict__ A, const short* __restrict__ Bp,
                const float* __restrict__ cn2,
                float* __restrict__ pval, int* __restrict__ pidx)
{
    __shared__ short Bs[2][3 * 4096];
    const int Ndim = CBB, Kdim = DD;
    const size_t NK = (size_t)Ndim * Kdim;
    const int tid = threadIdx.x;
    const int l   = tid & 63;
    const int w   = tid >> 6;

    int lin = xcd_remap_lin(blockIdx.y * gridDim.x + blockIdx.x, gridDim.x * gridDim.y);
    const int bxx = lin % gridDim.x;
    const int byy = lin / gridDim.x;

    const int wm0 = byy * 128 + w * 32;
    const int bn0 = bxx * 128;
    const int lr  = l & 15;
    const int lk  = (l >> 4) * 8;

    int sp[6], sn[6], sk[6];
    #pragma unroll
    for (int i = 0; i < 6; ++i) {
        int f = i * 4096 + tid * 16;
        sp[i] = f >> 13;
        int r = f & 8191;
        sn[i] = r >> 6;
        sk[i] = ((r & 63) >> 1) ^ (((sn[i] >> 1) & 3) << 3);
    }

    f32x4 acc[2][8];
    #pragma unroll
    for (int i = 0; i < 2; ++i)
        #pragma unroll
        for (int j = 0; j < 8; ++j)
            acc[i][j] = (f32x4){0.f, 0.f, 0.f, 0.f};

    #pragma unroll
    for (int i = 0; i < 6; ++i) {
        const short* src = Bp + (size_t)sp[i] * NK + (size_t)(bn0 + sn[i]) * Kdim + sk[i];
        gld_lds16(src, (short*)((char*)&Bs[0][0] + i * 4096 + w * 1024));
    }
    __syncthreads();

    int cur = 0;
    for (int k0 = 0; k0 < Kdim; k0 += 32) {
        if (k0 + 32 < Kdim) {
            #pragma unroll
            for (int i = 0; i < 6; ++i) {
                const short* src = Bp + (size_t)sp[i] * NK + (size_t)(bn0 + sn[i]) * Kdim + (k0 + 32) + sk[i];
                gld_lds16(src, (short*)((char*)&Bs[cur ^ 1][0] + i * 4096 + w * 1024));
            }
        }

        bf16x8 a0[2], a1[2], a2[2];
        #pragma unroll
        for (int mf = 0; mf < 2; ++mf) {
            const float* p = A + (size_t)(wm0 + mf * 16 + lr) * Kdim + k0 + lk;
            float v[8];
            *(float4*)&v[0] = *(const float4*)p;
            *(float4*)&v[4] = *(const float4*)(p + 4);
            cvt3x8(v, a0[mf], a1[mf], a2[mf]);
        }

        const short* Bh = &Bs[cur][0];
        #pragma unroll
        for (int nf = 0; nf < 8; ++nf) {
            int brow = nf * 16 + lr;
            int lkx = lk ^ (((brow >> 1) & 3) << 3);
            bf16x8 b0 = *(const bf16x8*)&Bh[0 * 4096 + brow * 32 + lkx];
            bf16x8 b1 = *(const bf16x8*)&Bh[1 * 4096 + brow * 32 + lkx];
            bf16x8 b2 = *(const bf16x8*)&Bh[2 * 4096 + brow * 32 + lkx];
            #pragma unroll
            for (int mf = 0; mf < 2; ++mf) {
                f32x4 c = acc[mf][nf];
                c = __builtin_amdgcn_mfma_f32_16x16x32_bf16(a0[mf], b0, c, 0, 0, 0);
                c = __builtin_amdgcn_mfma_f32_16x16x32_bf16(a0[mf], b1, c, 0, 0, 0);
                c = __builtin_amdgcn_mfma_f32_16x16x32_bf16(a1[mf], b0, c, 0, 0, 0);
                c = __builtin_amdgcn_mfma_f32_16x16x32_bf16(a1[mf], b1, c, 0, 0, 0);
                c = __builtin_amdgcn_mfma_f32_16x16x32_bf16(a0[mf], b2, c, 0, 0, 0);
                c = __builtin_amdgcn_mfma_f32_16x16x32_bf16(a2[mf], b0, c, 0, 0, 0);
                acc[mf][nf] = c;
            }
        }
        __syncthreads();
        cur ^= 1;
    }

    // fused argmin epilogue (ascending-n strict <, lane-reduce lower-idx tie-break)
    #pragma unroll
    for (int mf = 0; mf < 2; ++mf) {
        #pragma unroll
        for (int r = 0; r < 4; ++r) {
            int m = wm0 + mf * 16 + (l >> 4) * 4 + r;
            float best = INFINITY; int bi = 0x7fffffff;
            #pragma unroll
            for (int nf = 0; nf < 8; ++nf) {
                int n = bn0 + nf * 16 + lr;
                float d = cn2[n] - 2.0f * acc[mf][nf][r];
                if (d < best) { best = d; bi = n; }
            }
            #pragma unroll
            for (int off = 1; off < 16; off <<= 1) {
                float ov = __shfl_xor(best, off);
                int   oi = __shfl_xor(bi, off);
                if (ov < best || (ov == best && oi < bi)) { best = ov; bi = oi; }
            }
            if (lr == 0) {
                pval[(size_t)m * 8 + bxx] = best;
                pidx[(size_t)m * 8 + bxx] = bi;
            }
        }
    }
}

// ---------------- combine 8 per-block argmin partials ----------------
__global__ __launch_bounds__(256)
void argmin8_k(const float* __restrict__ pval, const int* __restrict__ pidx,
               int* __restrict__ idx)
{
    int row = blockIdx.x * 256 + threadIdx.x;
    float best = INFINITY; int bi = 0x7fffffff;
    #pragma unroll
    for (int j = 0; j < 8; ++j) {
        float v = pval[(size_t)row * 8 + j];
        int  ii = pidx[(size_t)row * 8 + j];
        if (v < best || (v == best && ii < bi)) { best = v; bi = ii; }
    }
    idx[row] = bi;
}

// ---------------- MFMA flash attention (LDS-staged from f32 qkv) ----------------
__global__ __launch_bounds__(256, 2)
void mattn_k(const float* __restrict__ qkv, float* __restrict__ o)
{
    const int bid = xcd_remap_lin(blockIdx.x, gridDim.x);
    const int qt = bid & 7;
    const int hh = (bid >> 3) & 7;
    const int bb = bid >> 6;
    const int tid = threadIdx.x;
    const int w  = tid >> 6;
    const int l  = tid & 63;
    const int lr = l & 15;
    const int lg = l >> 4;
    const int lk = lg * 8;

    __shared__ short Kb[3][4096];
    __shared__ short Vb[3][4096];
    __shared__ float Ps[4][1024];

    const float* qbase = qkv + (size_t)bb * TT * 1536 + hh * 64;
    const float* kbase = qbase + DD;
    const float* vbase = qbase + 2 * DD;

    bf16x8 qa[2][3];
    {
        int qrow = qt * 64 + w * 16 + lr;
        #pragma unroll
        for (int dc = 0; dc < 2; ++dc) {
            float v[8];
            const float* p = qbase + (size_t)qrow * 1536 + dc * 32 + lk;
            *(float4*)&v[0] = *(const float4*)p;
            *(float4*)&v[4] = *(const float4*)(p + 4);
            cvt3x8(v, qa[dc][0], qa[dc][1], qa[dc][2]);
        }
    }

    f32x4 oacc[4];
    #pragma unroll
    for (int nf = 0; nf < 4; ++nf) oacc[nf] = (f32x4){0.f, 0.f, 0.f, 0.f};
    float m[4], s[4];
    #pragma unroll
    for (int r = 0; r < 4; ++r) { m[r] = -INFINITY; s[r] = 0.f; }

    for (int kt = 0; kt <= qt; ++kt) {
        __syncthreads();
        {
            int kr = tid >> 2, dseg = (tid & 3) * 16;
            const float* p = kbase + (size_t)(kt * 64 + kr) * 1536 + dseg;
            float v[16];
            *(float4*)&v[0]  = *(const float4*)p;
            *(float4*)&v[4]  = *(const float4*)(p + 4);
            *(float4*)&v[8]  = *(const float4*)(p + 8);
            *(float4*)&v[12] = *(const float4*)(p + 12);
            bf16x8 t0, t1, t2, u0, u1, u2;
            cvt3x8(v, t0, t1, t2);
            cvt3x8(v + 8, u0, u1, u2);
            int si = (kr * 64 + dseg) ^ ((kr & 7) << 3);
            *(bf16x8*)&Kb[0][si] = t0; *(bf16x8*)&Kb[0][si ^ 8] = u0;
            *(bf16x8*)&Kb[1][si] = t1; *(bf16x8*)&Kb[1][si ^ 8] = u1;
            *(bf16x8*)&Kb[2][si] = t2; *(bf16x8*)&Kb[2][si ^ 8] = u2;
        }
        {
            int d = tid & 63, kg = (tid >> 6) * 16;
            const float* p = vbase + (size_t)(kt * 64 + kg) * 1536 + d;
            bf16x8 w0[2], w1[2], w2[2];
            #pragma unroll
            for (int i = 0; i < 16; ++i) {
                float f = p[(size_t)i * 1536];
                short h0, h1, h2; cvt3s(f, h0, h1, h2);
                w0[i >> 3][i & 7] = h0; w1[i >> 3][i & 7] = h1; w2[i >> 3][i & 7] = h2;
            }
            int si = (d * 64 + kg) ^ ((d & 7) << 3);
            *(bf16x8*)&Vb[0][si] = w0[0]; *(bf16x8*)&Vb[0][si ^ 8] = w0[1];
            *(bf16x8*)&Vb[1][si] = w1[0]; *(bf16x8*)&Vb[1][si ^ 8] = w1[1];
            *(bf16x8*)&Vb[2][si] = w2[0]; *(bf16x8*)&Vb[2][si ^ 8] = w2[1];
        }
        __syncthreads();

        f32x4 S4[4];
        #pragma unroll
        for (int nf = 0; nf < 4; ++nf) {
            f32x4 acc = (f32x4){0.f, 0.f, 0.f, 0.f};
            int kcol = nf * 16 + lr;
            int rowx = kcol * 64, sw = (kcol & 7) << 3;
            #pragma unroll
            for (int dc = 0; dc < 2; ++dc) {
                int si = rowx + ((dc * 32 + lk) ^ sw);
                bf16x8 b0 = *(const bf16x8*)&Kb[0][si];
                bf16x8 b1 = *(const bf16x8*)&Kb[1][si];
                bf16x8 b2 = *(const bf16x8*)&Kb[2][si];
                acc = __builtin_amdgcn_mfma_f32_16x16x32_bf16(qa[dc][0], b0, acc, 0, 0, 0);
                acc = __builtin_amdgcn_mfma_f32_16x16x32_bf16(qa[dc][0], b1, acc, 0, 0, 0);
                acc = __builtin_amdgcn_mfma_f32_16x16x32_bf16(qa[dc][1], b0, acc, 0, 0, 0);
                acc = __builtin_amdgcn_mfma_f32_16x16x32_bf16(qa[dc][1], b1, acc, 0, 0, 0);
                acc = __builtin_amdgcn_mfma_f32_16x16x32_bf16(qa[dc][0], b2, acc, 0, 0, 0);
                acc = __builtin_amdgcn_mfma_f32_16x16x32_bf16(qa[dc][2], b0, acc, 0, 0, 0);
            }
            S4[nf] = acc;
        }
        #pragma unroll
        for (int nf = 0; nf < 4; ++nf)
            #pragma unroll
            for (int r = 0; r < 4; ++r) S4[nf][r] *= 0.125f;
        if (kt == qt) {
            #pragma unroll
            for (int nf = 0; nf < 4; ++nf) {
                int kg_ = nf * 16 + lr;
                #pragma unroll
                for (int r = 0; r < 4; ++r) {
                    int qg_ = w * 16 + lg * 4 + r;
                    if (kg_ > qg_) S4[nf][r] = -INFINITY;
                }
            }
        }
        float mnew[4], scl[4], psum[4];
        #pragma unroll
        for (int r = 0; r < 4; ++r) {
            float v = fmaxf(fmaxf(S4[0][r], S4[1][r]), fmaxf(S4[2][r], S4[3][r]));
            v = fmaxf(v, __shfl_xor(v, 1));
            v = fmaxf(v, __shfl_xor(v, 2));
            v = fmaxf(v, __shfl_xor(v, 4));
            v = fmaxf(v, __shfl_xor(v, 8));
            mnew[r] = fmaxf(m[r], v);
            scl[r] = expf(m[r] - mnew[r]);
            psum[r] = 0.f;
        }
        #pragma unroll
        for (int nf = 0; nf < 4; ++nf) {
            #pragma unroll
            for (int r = 0; r < 4; ++r) {
                float p = expf(S4[nf][r] - mnew[r]);
                int row = lg * 4 + r;
                int col = nf * 16 + lr;
                Ps[w][row * 64 + (col ^ ((row & 7) << 3))] = p;
                psum[r] += p;
            }
        }
        #pragma unroll
        for (int r = 0; r < 4; ++r) {
            float v = psum[r];
            v += __shfl_xor(v, 1);
            v += __shfl_xor(v, 2);
            v += __shfl_xor(v, 4);
            v += __shfl_xor(v, 8);
            s[r] = s[r] * scl[r] + v;
            m[r] = mnew[r];
        }
        #pragma unroll
        for (int nf = 0; nf < 4; ++nf)
            #pragma unroll
            for (int r = 0; r < 4; ++r) oacc[nf][r] *= scl[r];

        #pragma unroll
        for (int kc = 0; kc < 2; ++kc) {
            int fi = lr * 64 + ((kc * 32 + lk) ^ ((lr & 7) << 3));
            float pv8[8];
            *(float4*)&pv8[0] = *(const float4*)&Ps[w][fi];
            *(float4*)&pv8[4] = *(const float4*)&Ps[w][fi + 4];
            bf16x8 pa0, pa1, pa2;
            cvt3x8(pv8, pa0, pa1, pa2);
            #pragma unroll
            for (int nf = 0; nf < 4; ++nf) {
                int drow = nf * 16 + lr;
                int si = drow * 64 + ((kc * 32 + lk) ^ ((drow & 7) << 3));
                bf16x8 b0 = *(const bf16x8*)&Vb[0][si];
                bf16x8 b1 = *(const bf16x8*)&Vb[1][si];
                bf16x8 b2 = *(const bf16x8*)&Vb[2][si];
                f32x4 c = oacc[nf];
                c = __builtin_amdgcn_mfma_f32_16x16x32_bf16(pa0, b0, c, 0, 0, 0);
                c = __builtin_amdgcn_mfma_f32_16x16x32_bf16(pa0, b1, c, 0, 0, 0);
                c = __builtin_amdgcn_mfma_f32_16x16x32_bf16(pa1, b0, c, 0, 0, 0);
                c = __builtin_amdgcn_mfma_f32_16x16x32_bf16(pa1, b1, c, 0, 0, 0);
                c = __builtin_amdgcn_mfma_f32_16x16x32_bf16(pa0, b2, c, 0, 0, 0);
                c = __builtin_amdgcn_mfma_f32_16x16x32_bf16(pa2, b0, c, 0, 0, 0);
                oacc[nf] = c;
            }
        }
    }

    #pragma unroll
    for (int nf = 0; nf < 4; ++nf) {
        #pragma unroll
        for (int r = 0; r < 4; ++r) {
            int qrow = qt * 64 + w * 16 + lg * 4 + r;
            o[(size_t)(bb * TT + qrow) * DD + hh * 64 + nf * 16 + lr] = oacc[nf][r] / s[r];
        }
    }
}

// ---------------- layernorm ----------------
__global__ __launch_bounds__(256)
void ln_k(const float* __restrict__ src, const float* __restrict__ s,
          const float* __restrict__ b, float* __restrict__ dst)
{
    __shared__ float red[256];
    const int row = blockIdx.x, t = threadIdx.x;
    const size_t base = (size_t)row * DD;
    float x0 = src[base + t], x1 = src[base + 256 + t];
    float mean = blk_reduce(x0 + x1, red) * (1.0f / 512.0f);
    float d0 = x0 - mean, d1 = x1 - mean;
    float var = blk_reduce(d0 * d0 + d1 * d1, red) * (1.0f / 512.0f);
    float inv = 1.0f / sqrtf(var + 1e-5f);
    dst[base + t]       = d0 * inv * s[t] + b[t];
    dst[base + 256 + t] = d1 * inv * s[t + 256] + b[t + 256];
}

// ---------------- codebook squared norms ----------------
__global__ __launch_bounds__(256)
void cn2_k(const float* __restrict__ cb, float* __restrict__ cn2)
{
    __shared__ float red[256];
    const int row = blockIdx.x, t = threadIdx.x;
    float a = cb[(size_t)row * DD + t], b = cb[(size_t)row * DD + 256 + t];
    float tot = blk_reduce(a * a + b * b, red);
    if (t == 0) cn2[row] = tot;
}

// ---------------- rotation trick + residual update + loss partial ----------------
__global__ __launch_bounds__(256)
void rotate_k(float* __restrict__ r, const float* __restrict__ cb,
              const int* __restrict__ idx, float* __restrict__ qo,
              float* __restrict__ lp)
{
    __shared__ float red[256];
    const int row = blockIdx.x, t = threadIdx.x;
    const size_t base = (size_t)row * DD;
    const float* qv = cb + (size_t)idx[row] * DD;
    float x0 = r[base + t], x1 = r[base + 256 + t];
    float q0 = qv[t], q1 = qv[t + 256];
    float nx2 = blk_reduce(x0 * x0 + x1 * x1, red);
    float nq2 = blk_reduce(q0 * q0 + q1 * q1, red);
    float dl0 = q0 - x0, dl1 = q1 - x1;
    float ls = blk_reduce(dl0 * dl0 + dl1 * dl1, red);
    if (t == 0) lp[row] = ls;
    const float eps = 1e-6f;
    float nx = sqrtf(nx2), nq = sqrtf(nq2);
    float mx = fmaxf(nx, eps), mq = fmaxf(nq, eps);
    float u0 = x0 / mx, u1 = x1 / mx;
    float qn0 = q0 / mq, qn1 = q1 / mq;
    float w0 = u0 + qn0, w1 = u1 + qn1;
    float nw2 = blk_reduce(w0 * w0 + w1 * w1, red);
    float mw = fmaxf(sqrtf(nw2), eps);
    w0 /= mw; w1 /= mw;
    float xw = blk_reduce(x0 * w0 + x1 * w1, red);
    float xu = blk_reduce(x0 * u0 + x1 * u1, red);
    float scl = nq / mx;
    float o0 = (x0 - 2.0f * xw * w0 + 2.0f * xu * qn0) * scl;
    float o1 = (x1 - 2.0f * xw * w1 + 2.0f * xu * qn1) * scl;
    r[base + t]        = x0 - o0;
    r[base + 256 + t]  = x1 - o1;
    qo[base + t]       += o0;
    qo[base + 256 + t] += o1;
}

// ---------------- commit loss reduce (f32 out) ----------------
__global__ __launch_bounds__(256)
void loss_k(const float* __restrict__ lp, float* __restrict__ out)
{
    __shared__ float red[256];
    const int t = threadIdx.x;
    float cm = 0.f;
    for (int qi = 0; qi < NQQ; ++qi) {
        float s = 0.f;
        for (int i = t; i < MM; i += 256) s += lp[qi * MM + i];
        float tot = blk_reduce(s, red);
        cm += 0.25f * (tot / (float)(MM * DD));
    }
    if (t == 0) out[0] = cm / (float)NQQ;
}

// ---------------- indices -> f32 output ----------------
__global__ __launch_bounds__(256)
void idxout_k(const int* __restrict__ idxw, float* __restrict__ out)
{
    int i = blockIdx.x * 256 + threadIdx.x;
    int row = i >> 2, qi = i & 3;
    out[i] = (float)idxw[qi * MM + row];
}

// ---------------- host launch ----------------
extern "C" void kernel_launch(void* const* d_in, const int* in_sizes, int n_in,
                              void* d_out, int out_size, void* d_ws, size_t ws_size,
                              hipStream_t stream)
{
    const float* x     = (const float*)d_in[0];
    const float* w_in  = (const float*)d_in[1];
    const float* b_in  = (const float*)d_in[2];
    const float* qkv_w = (const float*)d_in[3];
    const float* qkv_b = (const float*)d_in[4];
    const float* out_w = (const float*)d_in[5];
    const float* out_b = (const float*)d_in[6];
    const float* ln1_s = (const float*)d_in[7];
    const float* ln1_b = (const float*)d_in[8];
    const float* ln2_s = (const float*)d_in[9];
    const float* ln2_b = (const float*)d_in[10];
    const float* ff1_w = (const float*)d_in[11];
    const float* ff1_b = (const float*)d_in[12];
    const float* ff2_w = (const float*)d_in[13];
    const float* ff2_b = (const float*)d_in[14];
    const float* cbs   = (const float*)d_in[15];
    const float* dln_s = (const float*)d_in[16];
    const float* dln_b = (const float*)d_in[17];
    const float* dw1   = (const float*)d_in[18];
    const float* db1   = (const float*)d_in[19];
    const float* dw2   = (const float*)d_in[20];
    const float* db2   = (const float*)d_in[21];

    // ---- workspace: fixed 87.6 MB + chunk scratch ----
    float* ws  = (float*)d_ws;
    float* pe  = ws;                                   //   262,144 f
    float* h   = pe + (size_t)262144;                  // 8,388,608 f
    float* h2  = h + (size_t)MM * DD;                  // 8,388,608 f
    float* cn2 = h2 + (size_t)MM * DD;                 //     4,096 f
    float* lp  = cn2 + 4096;                           //    65,536 f
    int*   idxw = (int*)(lp + 65536);                  //    65,536 i
    short* wp  = (short*)(idxw + 65536);               // 9,437,184 shorts (18 MB shared planes)

    short* p_qkv = wp;                                  // 2,359,296
    short* p_out = wp + (size_t)2359296;                //   786,432
    short* p_ff1 = wp + (size_t)3145728;                // 3,145,728
    short* p_ff2 = wp + (size_t)6291456;                // 3,145,728
    short* p_win = wp;                                  //   393,216 (reuse, pre-loop)
    short* p_cb  = wp;                                  // 1,572,864 (reuse, VQ phase)
    short* p_dw1 = wp;                                  //   786,432 (reuse, decoder)
    short* p_dw2 = wp + (size_t)786432;                 //   393,216
    float* C = (float*)(wp + (size_t)9437184);

    size_t fixed_bytes = (size_t)((char*)C - (char*)ws);
    size_t cbytes = (ws_size > fixed_bytes) ? ws_size - fixed_bytes : 0;
    int CH = 32;
    while (CH > 1 && (size_t)CH * TT * 2048 * sizeof(float) > cbytes) CH >>= 1;
    const int NC = BB / CH;
    const int CR = CH * TT;

    float* qkvc  = C;                          // [CR][1536]
    float* attoc = C + (size_t)CR * 1536;      // [CR][512]
    float* midc  = C;                          // [CR][2048]
    float* pval  = C;                          // [CR][8] f (VQ partial vals)
    int*   pidx  = (int*)(C + (size_t)CR * 8); // [CR][8] i (VQ partial idx)
    float* dhc   = C;                          // [CR][512]
    float* dmidc = C + (size_t)CR * DD;        // [CR][512]

    // ---- prologue ----
    pe_k<<<dim3(512), dim3(256), 0, stream>>>(pe);
    cn2_k<<<dim3(NQQ * CBB), 256, 0, stream>>>(cbs, cn2);
    wsplit_tr_k<<<dim3(8, 4), 256, 0, stream>>>(w_in, p_win, 512, 256);
    mgemm2_k<EPI_PE><<<dim3(4, 128), 256, 0, stream>>>(x, p_win, b_in, pe, h, MM, DD, 256);

    for (int l = 0; l < NLL; ++l) {
        wsplit_tr_k<<<dim3(24, 8), 256, 0, stream>>>(qkv_w + (size_t)l * DD * 1536, p_qkv, 1536, 512);
        wsplit_tr_k<<<dim3(8, 8), 256, 0, stream>>>(out_w + (size_t)l * DD * DD, p_out, 512, 512);
        wsplit_tr_k<<<dim3(32, 8), 256, 0, stream>>>(ff1_w + (size_t)l * DD * 2048, p_ff1, 2048, 512);
        wsplit_tr_k<<<dim3(8, 32), 256, 0, stream>>>(ff2_w + (size_t)l * 2048 * DD, p_ff2, 512, 2048);
        for (int c = 0; c < NC; ++c) {
            float* hc  = h  + (size_t)c * CR * DD;
            float* h2c = h2 + (size_t)c * CR * DD;
            mgemm2_k<EPI_BIAS><<<dim3(12, CR / 128), 256, 0, stream>>>(
                hc, p_qkv, qkv_b + (size_t)l * 1536, nullptr, qkvc, CR, 1536, DD);
            mattn_k<<<dim3(CH * 64), 256, 0, stream>>>(qkvc, attoc);
            mgemm2_k<EPI_RES><<<dim3(4, CR / 128), 256, 0, stream>>>(
                attoc, p_out, out_b + (size_t)l * DD, hc, h2c, CR, DD, DD);
            ln_k<<<dim3(CR), 256, 0, stream>>>(h2c, ln1_s + (size_t)l * DD, ln1_b + (size_t)l * DD, h2c);
            mgemm2_k<EPI_RELU><<<dim3(16, CR / 128), 256, 0, stream>>>(
                h2c, p_ff1, ff1_b + (size_t)l * 2048, nullptr, midc, CR, 2048, DD);
            mgemm2_k<EPI_RES><<<dim3(4, CR / 128), 256, 0, stream>>>(
                midc, p_ff2, ff2_b + (size_t)l * DD, h2c, hc, CR, DD, 2048);
            ln_k<<<dim3(CR), 256, 0, stream>>>(hc, ln2_s + (size_t)l * DD, ln2_b + (size_t)l * DD, hc);
        }
    }

    // ---- residual VQ: fused dist GEMM + argmin partials, combine, rotate ----
    hipMemsetAsync(h2, 0, (size_t)MM * DD * sizeof(float), stream);
    for (int qi = 0; qi < NQQ; ++qi) {
        wsplit_dir_k<<<dim3(256), 256, 0, stream>>>(cbs + (size_t)qi * CBB * DD, p_cb, 512, 524288);
        for (int c = 0; c < NC; ++c) {
            float* hc = h + (size_t)c * CR * DD;
            distmin2_k<<<dim3(8, CR / 128), 256, 0, stream>>>(
                hc, p_cb, cn2 + qi * CBB, pval, pidx);
            argmin8_k<<<dim3(CR / 256), 256, 0, stream>>>(pval, pidx,
                                                          idxw + qi * MM + (size_t)c * CR);
        }
        rotate_k<<<dim3(MM), 256, 0, stream>>>(h, cbs + (size_t)qi * CBB * DD,
                                               idxw + qi * MM, h2, lp + qi * MM);
    }

    float* outf = (float*)d_out;
    loss_k<<<dim3(1), 256, 0, stream>>>(lp, outf + (size_t)MM * DATA);
    idxout_k<<<dim3(256), 256, 0, stream>>>(idxw, outf + (size_t)MM * DATA + 1);

    // ---- decoder ----
    wsplit_tr_k<<<dim3(8, 8), 256, 0, stream>>>(dw1, p_dw1, 512, 512);
    wsplit_tr_k<<<dim3(4, 8), 256, 0, stream>>>(dw2, p_dw2, 256, 512);
    for (int c = 0; c < NC; ++c) {
        float* h2c = h2 + (size_t)c * CR * DD;
        ln_k<<<dim3(CR), 256, 0, stream>>>(h2c, dln_s, dln_b, dhc);
        mgemm2_k<EPI_GELU><<<dim3(4, CR / 128), 256, 0, stream>>>(
            dhc, p_dw1, db1, nullptr, dmidc, CR, DD, DD);
        mgemm2_k<EPI_BIAS><<<dim3(2, CR / 128), 256, 0, stream>>>(
            dmidc, p_dw2, db2, nullptr, outf + (size_t)c * CR * DATA, CR, DATA, DD);
    }
}